// Round 8
// baseline (813.186 us; speedup 1.0000x reference)
//
#include <hip/hip_runtime.h>
#include <hip/hip_bf16.h>
#include <math.h>

// GraphConvLSTM: B=512, IN=256, H=128, T=100, N=22.
// Round 8: two-phase, 512 threads (8 waves, 4 waves/SIMD at 2 blocks/CU).
// Phase 1 (waves 0-3): G = A_norm @ (h @ W) entirely via MFMA:
//   MFMA1 (16x, hi/lo h split) -> C->B transform (12 shfl + cndmask + f16 hi/lo)
//   -> MFMA2 (6x, A_norm hi/lo) -> G written to col-XOR-swizzled LDS (b128 units).
// Phase 2 (all 8 waves): each thread reads 2 b128 G-units for its col, runs
// gates for 5-6 nodes. Trans cut to 5/element: shared-rcp 3-sigmoid +
// fma-form tanh (overflow-graceful, no clamps).

#define B_   512
#define IN_  256
#define H_   128
#define T_   100
#define N_   22
#define NH   (N_ * H_)      // 2816
#define TNH  (T_ * NH)      // 281600
#define HP   136            // padded h row length in fp16 elems
#define THREADS 512
#define LOG2E 1.442695041f

typedef __attribute__((ext_vector_type(8)))  _Float16 half8_t;  // fp16x8 MFMA frag
typedef __attribute__((ext_vector_type(16))) float    f32x16;   // 32x32 accumulator

#define D13 0.2773500981126146f
#define D5  0.4472135954999579f
#define D4  0.5f

__device__ __forceinline__ float dinv_of(int i) {
    return (i == 0 || i == 9) ? D13 : ((i == 3 || i == 6 || i == 12 || i == 15) ? D5 : D4);
}

__global__ void __launch_bounds__(THREADS, 4)
gclstm_kernel(const float* __restrict__ x,
              const float* __restrict__ wi_w, const float* __restrict__ wi_b,
              const float* __restrict__ wf_w, const float* __restrict__ wf_b,
              const float* __restrict__ wo_w, const float* __restrict__ wo_b,
              const float* __restrict__ wc_w, const float* __restrict__ wc_b,
              const float* __restrict__ gcn_w, const float* __restrict__ gcn_b,
              float* __restrict__ out)
{
    __shared__ __align__(16) _Float16 h_hi[32][HP];   // rows 22..31 stay zero
    __shared__ __align__(16) _Float16 h_lo[32][HP];
    __shared__ __align__(16) float    G_T[H_ * 32];   // [col][unit] 16B-swizzled
    __shared__ __align__(16) float    A_lds[32][32];  // normalized adjacency (padded)
    __shared__ float xp_lds[4][H_];
    __shared__ __align__(16) float xrow[IN_];

    const int t     = threadIdx.x;      // 0..511
    const int b     = blockIdx.x;
    const int lane  = t & 63;
    const int wid   = t >> 6;           // wave 0..7
    const int l31   = lane & 31;
    const int khalf = lane >> 5;
    const bool k0   = (khalf == 0);
    const int colW  = 32 * (wid & 3) + l31;   // phase-1 col (waves 0-3)
    const int col2  = t & (H_ - 1);           // phase-2 col
    const int q     = t >> 7;                 // quarter 0..3 (wave-uniform)

    // ---- stage x row; zero h and A_lds ----
    if (t < IN_ / 4) {
        reinterpret_cast<float4*>(xrow)[t] =
            reinterpret_cast<const float4*>(x + (size_t)b * IN_)[t];
    }
    for (int e = t; e < 32 * HP / 2; e += THREADS) ((int*)h_hi)[e] = 0;
    for (int e = t; e < 32 * HP / 2; e += THREADS) ((int*)h_lo)[e] = 0;
    for (int e = t; e < 32 * 32; e += THREADS) ((float*)A_lds)[e] = 0.0f;
    __syncthreads();

    // ---- x projection: thread computes gate q at channel col2 ----
    {
        const float* wg = (q == 0) ? wi_w : (q == 1) ? wf_w : (q == 2) ? wo_w : wc_w;
        const float* bg = (q == 0) ? wi_b : (q == 1) ? wf_b : (q == 2) ? wo_b : wc_b;
        const float* rg = wg + (size_t)col2 * IN_;
        float acc = bg[col2];
        #pragma unroll
        for (int k4 = 0; k4 < IN_ / 4; ++k4) {
            float4 xv = reinterpret_cast<const float4*>(xrow)[k4];
            float4 wv = reinterpret_cast<const float4*>(rg)[k4];
            acc += wv.x * xv.x + wv.y * xv.y + wv.z * xv.z + wv.w * xv.w;
        }
        xp_lds[q][col2] = acc;
    }

    // ---- build normalized adjacency (22x22 inside zeroed 32x32) ----
    if (t < N_ * N_) {
        const unsigned int masks[5] = {2341u, 1171u, 37449u, 2769408u, 1384960u};
        const int i = t / N_, j = t % N_;
        bool adj = false;
        if (i != j) {
            #pragma unroll
            for (int c = 0; c < 5; ++c)
                adj |= (((masks[c] >> i) & 1u) != 0u) && (((masks[c] >> j) & 1u) != 0u);
        }
        if (adj) A_lds[i][j] = dinv_of(i) * dinv_of(j);
    }
    __syncthreads();

    // ---- persistent fragments (phase-1 waves only) ----
    half8_t Wf[8];          // W B-frags: W[16kk+8khalf+i][colW]
    half8_t AtH[2], AtL[2]; // A_norm A-frags hi/lo: A[l31][16kt+8khalf+i]
    if (wid < 4) {
        #pragma unroll
        for (int kk = 0; kk < 8; ++kk)
            #pragma unroll
            for (int i = 0; i < 8; ++i)
                Wf[kk][i] = (_Float16)gcn_w[(16 * kk + 8 * khalf + i) * H_ + colW];
        #pragma unroll
        for (int kt = 0; kt < 2; ++kt)
            #pragma unroll
            for (int i = 0; i < 8; ++i) {
                const float a = A_lds[l31][16 * kt + 8 * khalf + i];
                const _Float16 ah = (_Float16)a;
                AtH[kt][i] = ah;
                AtL[kt][i] = (_Float16)(a - (float)ah);
            }
    }

    // ---- per-thread step-invariant gate constants (channel col2) ----
    const float gb  = gcn_b[col2];
    const float Ei  = __builtin_exp2f(-LOG2E * (xp_lds[0][col2] + gb));
    const float Ef  = __builtin_exp2f(-LOG2E * (xp_lds[1][col2] + gb));
    const float Eo  = __builtin_exp2f(-LOG2E * (xp_lds[2][col2] + gb));
    const float E2c = __builtin_exp2f(-2.0f * LOG2E * (xp_lds[3][col2] + gb));

    float c_reg[6];
    #pragma unroll
    for (int i = 0; i < 6; ++i) c_reg[i] = 0.0f;

    float* outb = out + (size_t)b * TNH + col2;
    const int swW = colW & 7;
    const int sw2 = col2 & 7;

    for (int step = 0; step < T_; ++step) {
        // ============ phase 1: G = A_norm @ (h @ W), all MFMA (waves 0-3) ============
        if (wid < 4) {
            f32x16 accA = (f32x16)(0.0f);
            f32x16 accB = (f32x16)(0.0f);
            #pragma unroll
            for (int kk = 0; kk < 8; ++kk) {
                const int ko = 16 * kk + 8 * khalf;
                const half8_t Ah = *reinterpret_cast<const half8_t*>(&h_hi[l31][ko]);
                const half8_t Al = *reinterpret_cast<const half8_t*>(&h_lo[l31][ko]);
                accA = __builtin_amdgcn_mfma_f32_32x32x16_f16(Ah, Wf[kk], accA, 0, 0, 0);
                accB = __builtin_amdgcn_mfma_f32_32x32x16_f16(Al, Wf[kk], accB, 0, 0, 0);
            }
            // Y rows at this lane: 8q'+4khalf+i (q'<3 real, q'=3 -> rows>=24 unused)
            float y[12], z[12];
            #pragma unroll
            for (int s = 0; s < 12; ++s) y[s] = accA[s] + accB[s];
            #pragma unroll
            for (int s = 0; s < 12; ++s) z[s] = __shfl_xor(y[s], 32, 64);

            // B-frags for MFMA2: B[k=row][colW]; ktile a: rows 0-15, b: rows 16-31
            float ba[8], bb[8];
            #pragma unroll
            for (int i = 0; i < 4; ++i) {
                ba[i]     = k0 ? y[i]     : z[4 + i];   // rows 0-3 | 8-11
                ba[4 + i] = k0 ? z[i]     : y[4 + i];   // rows 4-7 | 12-15
                bb[i]     = y[8 + i];                   // rows 16-19 | (junk, A=0)
                bb[4 + i] = z[8 + i];                   // rows 20-23 | (junk, A=0)
            }
            half8_t BaH, BaL, BbH, BbL;
            #pragma unroll
            for (int i = 0; i < 8; ++i) {
                const _Float16 h1 = (_Float16)ba[i];
                BaH[i] = h1;  BaL[i] = (_Float16)(ba[i] - (float)h1);
                const _Float16 h2 = (_Float16)bb[i];
                BbH[i] = h2;  BbL[i] = (_Float16)(bb[i] - (float)h2);
            }
            f32x16 gA = (f32x16)(0.0f);
            gA = __builtin_amdgcn_mfma_f32_32x32x16_f16(AtH[0], BaH, gA, 0, 0, 0);
            gA = __builtin_amdgcn_mfma_f32_32x32x16_f16(AtH[1], BbH, gA, 0, 0, 0);
            gA = __builtin_amdgcn_mfma_f32_32x32x16_f16(AtH[0], BaL, gA, 0, 0, 0);
            gA = __builtin_amdgcn_mfma_f32_32x32x16_f16(AtH[1], BbL, gA, 0, 0, 0);
            gA = __builtin_amdgcn_mfma_f32_32x32x16_f16(AtL[0], BaH, gA, 0, 0, 0);
            gA = __builtin_amdgcn_mfma_f32_32x32x16_f16(AtL[1], BbH, gA, 0, 0, 0);

            // write G units: unit 2q'+khalf holds rows 8q'+4khalf..+3 at colW
            #pragma unroll
            for (int qq = 0; qq < 3; ++qq) {
                float4 v = make_float4(gA[4 * qq], gA[4 * qq + 1],
                                       gA[4 * qq + 2], gA[4 * qq + 3]);
                const int unit = (2 * qq + khalf) ^ swW;
                *reinterpret_cast<float4*>(&G_T[colW * 32 + unit * 4]) = v;
            }
        }
        __syncthreads();

        // ============ phase 2: gates, 5-6 nodes per thread ============
        int UA, UB;
        if      (q == 0) { UA = 0; UB = 1; }
        else if (q == 1) { UA = 1; UB = 2; }
        else if (q == 2) { UA = 2; UB = 3; }
        else             { UA = 4; UB = 5; }
        const float4 va = *reinterpret_cast<const float4*>(&G_T[col2 * 32 + ((UA ^ sw2) << 2)]);
        const float4 vb = *reinterpret_cast<const float4*>(&G_T[col2 * 32 + ((UB ^ sw2) << 2)]);

        float* outs = outb + (size_t)step * NH;

        #define UPDN(n, sl, gval) {                                             \
            const float E  = __builtin_exp2f(-LOG2E * (gval));                  \
            const float u  = __builtin_fmaf(E, Ei, 1.0f);                       \
            const float v  = __builtin_fmaf(E, Ef, 1.0f);                       \
            const float w  = __builtin_fmaf(E, Eo, 1.0f);                       \
            const float uv = u * v, vw = v * w, uw = u * w;                     \
            const float rP = __builtin_amdgcn_rcpf(uv * w);                     \
            const float it = vw * rP, ft = uw * rP, ot = uv * rP;               \
            const float e2 = E * E * E2c;                                       \
            const float ct = __builtin_fmaf(2.0f,                               \
                                __builtin_amdgcn_rcpf(1.0f + e2), -1.0f);       \
            const float cn = __builtin_fmaf(ft, c_reg[sl], it * ct);            \
            c_reg[sl] = cn;                                                     \
            const float en = __builtin_exp2f((2.0f * LOG2E) * cn);              \
            const float th = __builtin_fmaf(-2.0f,                              \
                                __builtin_amdgcn_rcpf(1.0f + en), 1.0f);        \
            const float hn = ot * th;                                           \
            outs[(n) * H_] = hn;                                                \
            const _Float16 hh = (_Float16)hn;                                   \
            h_hi[n][col2] = hh;                                                 \
            h_lo[n][col2] = (_Float16)(hn - (float)hh);                         \
        }

        if (q == 0) {            // nodes 0-5 (rows 0-5: unit0 + unit1[0:2])
            UPDN(0, 0, va.x) UPDN(1, 1, va.y) UPDN(2, 2, va.z)
            UPDN(3, 3, va.w) UPDN(4, 4, vb.x) UPDN(5, 5, vb.y)
        } else if (q == 1) {     // nodes 6-10 (rows 6-7: unit1[2:4]; 8-10: unit2)
            UPDN(6, 0, va.z) UPDN(7, 1, va.w) UPDN(8, 2, vb.x)
            UPDN(9, 3, vb.y) UPDN(10, 4, vb.z)
        } else if (q == 2) {     // nodes 11-15 (row 11: unit2[3]; 12-15: unit3)
            UPDN(11, 0, va.w) UPDN(12, 1, vb.x) UPDN(13, 2, vb.y)
            UPDN(14, 3, vb.z) UPDN(15, 4, vb.w)
        } else {                 // nodes 16-21 (16-19: unit4; 20-21: unit5[0:2])
            UPDN(16, 0, va.x) UPDN(17, 1, va.y) UPDN(18, 2, va.z)
            UPDN(19, 3, va.w) UPDN(20, 4, vb.x) UPDN(21, 5, vb.y)
        }
        #undef UPDN

        __syncthreads();   // h fully written -> next step's MFMA reads
    }
}

extern "C" void kernel_launch(void* const* d_in, const int* in_sizes, int n_in,
                              void* d_out, int out_size, void* d_ws, size_t ws_size,
                              hipStream_t stream) {
    const float* x     = (const float*)d_in[0];
    const float* wi_w  = (const float*)d_in[1];
    const float* wi_b  = (const float*)d_in[2];
    const float* wf_w  = (const float*)d_in[3];
    const float* wf_b  = (const float*)d_in[4];
    const float* wo_w  = (const float*)d_in[5];
    const float* wo_b  = (const float*)d_in[6];
    const float* wc_w  = (const float*)d_in[7];
    const float* wc_b  = (const float*)d_in[8];
    const float* gcn_w = (const float*)d_in[9];
    const float* gcn_b = (const float*)d_in[10];
    float* out = (float*)d_out;

    gclstm_kernel<<<dim3(B_), dim3(THREADS), 0, stream>>>(
        x, wi_w, wi_b, wf_w, wf_b, wo_w, wo_b, wc_w, wc_b, gcn_w, gcn_b, out);
}